// Round 2
// baseline (418.286 us; speedup 1.0000x reference)
//
#include <hip/hip_runtime.h>
#include <hip/hip_bf16.h>

typedef __attribute__((ext_vector_type(8))) short short8;     // 8 bf16 (4 VGPRs) MFMA frag
typedef __attribute__((ext_vector_type(4))) float f32x4;
typedef __attribute__((ext_vector_type(4))) unsigned int uint4v;

#define NROW 29
#define CCH 64
#define XSTRIDE 1856        // 29*64 floats per edge
#define N0SQ (448*448)
#define N1SQ (768*768)
#define N2SQ (640*640)

// m-order -> lp-order row permutation (TO_M)
__constant__ int d_TO_M[29] = {0,2,6,11,16,21,26, 3,7,12,17,22,27, 1,5,10,15,20,25,
                               8,13,18,23,28, 4,9,14,19,24};

__device__ __forceinline__ short f2bf(float f) {
    __hip_bfloat16 h = __float2bfloat16(f);
    return __builtin_bit_cast(short, h);
}

// Build effective bf16 weights in ws: Wb0 = W0; Wb1/Wb2 = [[Wr,-Wi],[Wi,Wr]] layout [n][k]
__global__ __launch_bounds__(256) void prep_weights(const float* __restrict__ W0,
                                                    const float* __restrict__ W1,
                                                    const float* __restrict__ W2,
                                                    short* __restrict__ ws) {
    int idx = blockIdx.x * 256 + threadIdx.x;
    if (idx < N0SQ) {
        ws[idx] = f2bf(W0[idx]);
        return;
    }
    idx -= N0SQ;
    if (idx < N1SQ) {
        int n = idx / 768, k = idx % 768;
        int no = n / 384, ni = n % 384;
        int ko = k / 384, ki = k % 384;
        float v;
        if (no == ko)      v =  W1[ni * 384 + ki];
        else if (no == 0)  v = -W1[(384 + ni) * 384 + ki];
        else               v =  W1[(384 + ni) * 384 + ki];
        ws[N0SQ + idx] = f2bf(v);
        return;
    }
    idx -= N1SQ;
    if (idx < N2SQ) {
        int n = idx / 640, k = idx % 640;
        int no = n / 320, ni = n % 320;
        int ko = k / 320, ki = k % 320;
        float v;
        if (no == ko)      v =  W2[ni * 320 + ki];
        else if (no == 0)  v = -W2[(320 + ni) * 320 + ki];
        else               v =  W2[(320 + ni) * 320 + ki];
        ws[N0SQ + N1SQ + idx] = f2bf(v);
    }
}

// 128(edges) x 128(cols) tile, BK=32, 4 waves x (64x64), mfma 16x16x32 bf16.
// Double-buffered LDS, ONE barrier per k-step, A 2-iter-deep reg prefetch, B 1-deep.
// LDS row stride 32 bf16 (64 B): b128 read AND write patterns hit 8 lanes per
// 4-bank cluster = structural minimum -> no pad, no swizzle needed.
__global__ __launch_bounds__(256) void so2_gemm(const float* __restrict__ x,
                                                const float* __restrict__ b0,
                                                const short* __restrict__ wsW,
                                                float* __restrict__ out,
                                                int E, int nwg) {
    // bijective XCD chunk swizzle (m204): one etile's 15 n-tiles share an XCD's L2
    int orig = blockIdx.x;
    int q8 = nwg >> 3, r8 = nwg & 7;
    int xcd = orig & 7, pos = orig >> 3;
    int wgid = (xcd < r8 ? xcd * (q8 + 1) : r8 * (q8 + 1) + (xcd - r8) * q8) + pos;

    int etile = wgid / 15;
    int ncol  = wgid % 15;
    int blk, ntl;
    if (ncol < 4)       { blk = 0; ntl = ncol; }
    else if (ncol < 10) { blk = 1; ntl = ncol - 4; }
    else                { blk = 2; ntl = ncol - 10; }
    const int Kb     = (blk == 0) ? 448 : (blk == 1) ? 768 : 640;   // square blocks
    const int ksteps = Kb >> 5;                                     // 14 / 24 / 20 (even)
    const int kbase  = (blk == 0) ? 0 : (blk == 1) ? 7 : 19;
    const int nrows  = (blk == 0) ? 7 : (blk == 1) ? 12 : 10;
    const long woff  = (blk == 0) ? 0 : (blk == 1) ? (long)N0SQ : (long)(N0SQ + N1SQ);
    const short* Wb  = wsW + woff;

    __shared__ short Alds[2][128 * 32];   // 8 KB per buffer
    __shared__ short Blds[2][128 * 32];   // total 32 KB

    const int tid  = threadIdx.x;
    const int w    = tid >> 6, lane = tid & 63;
    const int wr   = w >> 1,   wc   = w & 1;
    const int lrow = lane & 15, lk  = lane >> 4;
    const int ebase = etile * 128;

    // staging geometry: thread owns rows qr and 64+qr, k-quarter rq (8 elems each)
    const int qr = tid >> 2;
    const int rq = tid & 3;

    const int e1 = ebase + qr,      e2 = ebase + 64 + qr;
    const bool eok1 = e1 < E,       eok2 = e2 < E;
    const int n1 = ntl * 128 + qr,  n2 = n1 + 64;
    const bool nok1 = n1 < Kb,      nok2 = n2 < Kb;   // blk0 tail tile: zero rows

    const float* xb1 = x + (size_t)e1 * XSTRIDE + rq * 8;
    const float* xb2 = x + (size_t)e2 * XSTRIDE + rq * 8;
    const short* wb1 = Wb + (size_t)n1 * Kb + rq * 8;
    const short* wb2 = Wb + (size_t)n2 * Kb + rq * 8;

    f32x4 acc[4][4] = {};

    f32x4 sA0[4], sA1[4];   // A staging, 2 stages (even/odd tiles)
    uint4v sB[2];           // B staging, 1 stage (L2-hot, 1 iter of cover suffices)

    auto issueA = [&](int kt, f32x4* ar) {
        int g = d_TO_M[kbase + (kt >> 1)];
        size_t off = (size_t)g * CCH + (size_t)((kt & 1) * 32);
        if (eok1) { ar[0] = *(const f32x4*)(xb1 + off); ar[1] = *(const f32x4*)(xb1 + off + 4); }
        else      { ar[0] = f32x4{0,0,0,0};             ar[1] = f32x4{0,0,0,0}; }
        if (eok2) { ar[2] = *(const f32x4*)(xb2 + off); ar[3] = *(const f32x4*)(xb2 + off + 4); }
        else      { ar[2] = f32x4{0,0,0,0};             ar[3] = f32x4{0,0,0,0}; }
    };
    auto issueB = [&](int kt) {
        int off = kt * 32;
        sB[0] = nok1 ? *(const uint4v*)(wb1 + off) : uint4v{0,0,0,0};
        sB[1] = nok2 ? *(const uint4v*)(wb2 + off) : uint4v{0,0,0,0};
    };
    auto writeL = [&](int pb, const f32x4* ar) {
        short8 h0, h1;
#pragma unroll
        for (int j = 0; j < 4; ++j) {
            h0[j]     = f2bf(ar[0][j]);  h0[4 + j] = f2bf(ar[1][j]);
            h1[j]     = f2bf(ar[2][j]);  h1[4 + j] = f2bf(ar[3][j]);
        }
        *(short8*)&Alds[pb][qr * 32 + rq * 8]        = h0;
        *(short8*)&Alds[pb][(64 + qr) * 32 + rq * 8] = h1;
        *(uint4v*)&Blds[pb][qr * 32 + rq * 8]        = sB[0];
        *(uint4v*)&Blds[pb][(64 + qr) * 32 + rq * 8] = sB[1];
    };
    auto compute = [&](int pb) {
        short8 af[4], bf[4];
#pragma unroll
        for (int mf = 0; mf < 4; ++mf)
            af[mf] = *(short8*)&Alds[pb][(wr * 64 + mf * 16 + lrow) * 32 + lk * 8];
#pragma unroll
        for (int nf = 0; nf < 4; ++nf)
            bf[nf] = *(short8*)&Blds[pb][(wc * 64 + nf * 16 + lrow) * 32 + lk * 8];
#pragma unroll
        for (int mf = 0; mf < 4; ++mf)
#pragma unroll
            for (int nf = 0; nf < 4; ++nf)
                acc[mf][nf] = __builtin_amdgcn_mfma_f32_16x16x32_bf16(af[mf], bf[nf], acc[mf][nf], 0, 0, 0);
    };

    // prologue: tile0 -> LDS buf0; tile1 in sA1/sB; tile2 A-loads in flight
    issueA(0, sA0); issueB(0);
    issueA(1, sA1);
    writeL(0, sA0);
    issueB(1);
    issueA(2, sA0);
    __syncthreads();                      // buf0 ready

    for (int kt = 0; kt < ksteps; kt += 2) {
        // even iter: compute tile kt from buf0
        writeL(1, sA1);                   // tile kt+1 (regs had >=1 full iter to land)
        if (kt + 2 < ksteps) {
            issueB(kt + 2);
            issueA(kt + 3, sA1);          // consumed 2 iterations from now
        }
        compute(0);
        __syncthreads();
        // odd iter: compute tile kt+1 from buf1
        if (kt + 2 < ksteps) {
            writeL(0, sA0);               // tile kt+2
            issueB(kt + 3);               // kt+3 <= ksteps-1 guaranteed (ksteps even)
            if (kt + 4 < ksteps) issueA(kt + 4, sA0);
        }
        compute(1);
        __syncthreads();
    }

    // epilogue: wave's 64 cols = output m-row (ntl*2 + wc); store to lp-row TO_M[...]
    int mrow_l = ntl * 2 + wc;
    if (mrow_l < nrows) {
        int lp = d_TO_M[kbase + mrow_l];
        float* op = out + (size_t)lp * CCH;
#pragma unroll
        for (int nf = 0; nf < 4; ++nf) {
            int c = nf * 16 + lrow;
            float bias = 0.f;
            if (blk == 0) bias = b0[mrow_l * 64 + c];
#pragma unroll
            for (int mf = 0; mf < 4; ++mf) {
                int e0 = ebase + wr * 64 + mf * 16 + lk * 4;
#pragma unroll
                for (int j = 0; j < 4; ++j) {
                    int e = e0 + j;
                    if (e < E) op[(size_t)e * XSTRIDE + c] = acc[mf][nf][j] + bias;
                }
            }
        }
    }
}

extern "C" void kernel_launch(void* const* d_in, const int* in_sizes, int n_in,
                              void* d_out, int out_size, void* d_ws, size_t ws_size,
                              hipStream_t stream) {
    const float* x_emb = (const float*)d_in[0];
    // d_in[1] = x_edge: unused by the reference
    const float* W0 = (const float*)d_in[2];
    const float* b0 = (const float*)d_in[3];
    const float* W1 = (const float*)d_in[4];
    const float* W2 = (const float*)d_in[5];
    float* out = (float*)d_out;
    short* ws  = (short*)d_ws;   // bf16 effective weights, 2,400,256 B

    const int E = in_sizes[0] / (NROW * CCH);

    const int prep_total = N0SQ + N1SQ + N2SQ;
    prep_weights<<<(prep_total + 255) / 256, 256, 0, stream>>>(W0, W1, W2, ws);

    const int etiles = (E + 127) / 128;
    const int nwg = etiles * 15;
    so2_gemm<<<nwg, 256, 0, stream>>>(x_emb, b0, (const short*)ws, out, E, nwg);
}